// Round 6
// baseline (2579.669 us; speedup 1.0000x reference)
//
#include <hip/hip_runtime.h>

#define N_NODES 100000
#define N_EDGES 1600000
#define N_LABEL 200000
#define C_IN 128
#define C_HID 256
#define C_OUT 128

#define BCHUNK 64                                 // nodes per bucket
#define NBUCK ((N_NODES + BCHUNK - 1) / BCHUNK)   // 1563
#define NBF 64                                    // multisplit blocks
#define EPB (N_EDGES / NBF)                       // 25000 edges per block
#define FLEN (NBUCK * NBF)                        // 100032 (bucket-major counts)

typedef __attribute__((ext_vector_type(8))) short bf16x8;
typedef __attribute__((ext_vector_type(4))) float f32x4;

__device__ __forceinline__ ushort f2bf(float f) {  // RTNE
  uint u = __float_as_uint(f);
  return (ushort)((u + 0x7fffu + ((u >> 16) & 1u)) >> 16);
}

__device__ __forceinline__ void async_copy16(const void* g, void* lds) {
  __builtin_amdgcn_global_load_lds((const __attribute__((address_space(1))) void*)g,
                                   (__attribute__((address_space(3))) void*)lds,
                                   16, 0, 0);
}

// ---------------------------------------------------------------------------
// Multisplit P1: per-(block,bucket) histogram. LDS counters (chains ~16).
// cnt layout: [bucket][block]  (bucket-major so the scan order gives
// bucket-contiguous regions, blocks stable within bucket).
// ---------------------------------------------------------------------------
__global__ __launch_bounds__(256) void bucket_count(const int* __restrict__ dst,
                                                    int* __restrict__ cnt) {
  __shared__ int lcnt[NBUCK];
  const int t = threadIdx.x;
  const int base = blockIdx.x * EPB;
  for (int b = t; b < NBUCK; b += 256) lcnt[b] = 0;
  __syncthreads();
  for (int i = t; i < EPB; i += 256) {
    atomicAdd(&lcnt[dst[base + i] >> 6], 1);
  }
  __syncthreads();
  for (int b = t; b < NBUCK; b += 256) cnt[b * NBF + blockIdx.x] = lcnt[b];
}

// ---------------------------------------------------------------------------
// Generic 3-phase exclusive scan (in place), length LEN.
// ---------------------------------------------------------------------------
template <int LEN>
__global__ __launch_bounds__(256) void scan_sums(const int* __restrict__ a,
                                                 int* __restrict__ bsum) {
  __shared__ int red[256];
  const int t = threadIdx.x;
  const int idx = blockIdx.x * 1024 + t * 4;
  int s = 0;
  if (idx + 3 < LEN) {
    const int4 v = *(const int4*)&a[idx];
    s = v.x + v.y + v.z + v.w;
  } else {
    for (int j = 0; j < 4 && idx + j < LEN; ++j) s += a[idx + j];
  }
  red[t] = s;
  __syncthreads();
  for (int off = 128; off > 0; off >>= 1) {
    if (t < off) red[t] += red[t + off];
    __syncthreads();
  }
  if (t == 0) bsum[blockIdx.x] = red[0];
}

__global__ __launch_bounds__(128) void scan_tops(const int* __restrict__ bsum,
                                                 int* __restrict__ bpre,
                                                 int* __restrict__ total, int nb) {
  __shared__ int sh[128];
  const int t = threadIdx.x;
  sh[t] = (t < nb) ? bsum[t] : 0;
  __syncthreads();
  for (int off = 1; off < 128; off <<= 1) {
    int v = 0;
    if (t >= off) v = sh[t - off];
    __syncthreads();
    if (t >= off) sh[t] += v;
    __syncthreads();
  }
  if (t < nb) bpre[t] = (t == 0) ? 0 : sh[t - 1];
  if (t == nb - 1) *total = sh[t];
}

template <int LEN>
__global__ __launch_bounds__(256) void scan_apply(int* __restrict__ a,
                                                  const int* __restrict__ bpre) {
  __shared__ int sh[256];
  const int t = threadIdx.x;
  const int idx = blockIdx.x * 1024 + t * 4;
  int4 v = make_int4(0, 0, 0, 0);
  const bool full = (idx + 3 < LEN);
  if (full) {
    v = *(const int4*)&a[idx];
  } else {
    if (idx + 0 < LEN) v.x = a[idx + 0];
    if (idx + 1 < LEN) v.y = a[idx + 1];
    if (idx + 2 < LEN) v.z = a[idx + 2];
    if (idx + 3 < LEN) v.w = a[idx + 3];
  }
  sh[t] = v.x + v.y + v.z + v.w;
  __syncthreads();
  for (int off = 1; off < 256; off <<= 1) {
    int u = 0;
    if (t >= off) u = sh[t - off];
    __syncthreads();
    if (t >= off) sh[t] += u;
    __syncthreads();
  }
  const int base = bpre[blockIdx.x] + ((t == 0) ? 0 : sh[t - 1]);
  int4 e;
  e.x = base;
  e.y = base + v.x;
  e.z = base + v.x + v.y;
  e.w = base + v.x + v.y + v.z;
  if (full) {
    *(int4*)&a[idx] = e;
  } else {
    if (idx + 0 < LEN) a[idx + 0] = e.x;
    if (idx + 1 < LEN) a[idx + 1] = e.y;
    if (idx + 2 < LEN) a[idx + 2] = e.z;
    if (idx + 3 < LEN) a[idx + 3] = e.w;
  }
}

// ---------------------------------------------------------------------------
// Multisplit P3: deterministic scatter. LDS cursors seeded from the scanned
// cnt (no global atomics); each (block,bucket) run is ~16 contiguous entries
// written from one CU -> dense lines. Entry = (src<<6)|(dst&63).
// ---------------------------------------------------------------------------
__global__ __launch_bounds__(256) void bucket_fill(const int* __restrict__ src,
                                                   const int* __restrict__ dst,
                                                   const int* __restrict__ cnt,
                                                   uint* __restrict__ tmp) {
  __shared__ int lcur[NBUCK];
  const int t = threadIdx.x;
  const int base = blockIdx.x * EPB;
  for (int b = t; b < NBUCK; b += 256) lcur[b] = cnt[b * NBF + blockIdx.x];
  __syncthreads();
  for (int i = t; i < EPB; i += 256) {
    const int d = dst[base + i];
    const int s = src[base + i];
    const int pos = atomicAdd(&lcur[d >> 6], 1);
    tmp[pos] = ((uint)s << 6) | (uint)(d & 63);
  }
}

// ---------------------------------------------------------------------------
// Bucketed mean aggregation: one block per 64-node bucket. 32KB LDS fp32
// accumulator [64 nodes][128 ch]; waves stream the bucket's entries, read the
// 256B bf16 feat row coalesced, ds_add into LDS. Degree counted in LDS.
// MODE 0: write bf16 mean to bout.  MODE 1: z[node] += mean (fp32).
// ---------------------------------------------------------------------------
template <int MODE>
__global__ __launch_bounds__(256) void agg_bucket(const int* __restrict__ cnt,
                                                  const uint* __restrict__ tmp,
                                                  const ushort* __restrict__ feat,
                                                  ushort* __restrict__ bout,
                                                  float* __restrict__ z) {
  __shared__ float acc[BCHUNK][128];  // 32 KB
  __shared__ int ldeg[BCHUNK];
  const int b = blockIdx.x;
  const int t = threadIdx.x;
  const int w = t >> 6;
  const int l = t & 63;
  float* af = &acc[0][0];
  for (int i = t; i < BCHUNK * 128; i += 256) af[i] = 0.f;
  if (t < BCHUNK) ldeg[t] = 0;
  __syncthreads();
  const int s = cnt[b * NBF];
  const int e = cnt[(b + 1) * NBF];  // b==NBUCK-1 -> cnt[FLEN] == N_EDGES
  int j = s + w;
  for (; j + 4 < e; j += 8) {
    const uint v0 = tmp[j];
    const uint v1 = tmp[j + 4];
    const uint p0 = *(const uint*)&feat[(size_t)(v0 >> 6) * 128 + l * 2];
    const uint p1 = *(const uint*)&feat[(size_t)(v1 >> 6) * 128 + l * 2];
    const int d0 = v0 & 63;
    const int d1 = v1 & 63;
    atomicAdd(&acc[d0][l * 2], __uint_as_float(p0 << 16));
    atomicAdd(&acc[d0][l * 2 + 1], __uint_as_float(p0 & 0xffff0000u));
    if (l == 0) atomicAdd(&ldeg[d0], 1);
    atomicAdd(&acc[d1][l * 2], __uint_as_float(p1 << 16));
    atomicAdd(&acc[d1][l * 2 + 1], __uint_as_float(p1 & 0xffff0000u));
    if (l == 0) atomicAdd(&ldeg[d1], 1);
  }
  if (j < e) {
    const uint v0 = tmp[j];
    const uint p0 = *(const uint*)&feat[(size_t)(v0 >> 6) * 128 + l * 2];
    const int d0 = v0 & 63;
    atomicAdd(&acc[d0][l * 2], __uint_as_float(p0 << 16));
    atomicAdd(&acc[d0][l * 2 + 1], __uint_as_float(p0 & 0xffff0000u));
    if (l == 0) atomicAdd(&ldeg[d0], 1);
  }
  __syncthreads();
  for (int nl = w; nl < BCHUNK; nl += 4) {
    const int node = b * BCHUNK + nl;
    if (node >= N_NODES) break;
    const float rd = 1.f / fmaxf((float)ldeg[nl], 1.f);
    const float m0 = acc[nl][l * 2] * rd;
    const float m1 = acc[nl][l * 2 + 1] * rd;
    if (MODE == 0) {
      *(uint*)&bout[(size_t)node * 128 + l * 2] =
          (uint)f2bf(m0) | ((uint)f2bf(m1) << 16);
    } else {
      float2 zv = *(const float2*)&z[(size_t)node * 128 + l * 2];
      zv.x += m0;
      zv.y += m1;
      *(float2*)&z[(size_t)node * 128 + l * 2] = zv;
    }
  }
}

// ---------------------------------------------------------------------------
// fp32 -> bf16 cast (8 elems / thread)
// ---------------------------------------------------------------------------
__global__ __launch_bounds__(256) void cast_bf16(const float* __restrict__ in,
                                                 ushort* __restrict__ out) {
  const size_t i = ((size_t)blockIdx.x * 256 + threadIdx.x) * 8;
  const float4 a = *(const float4*)&in[i];
  const float4 b = *(const float4*)&in[i + 4];
  uint4 o;
  o.x = (uint)f2bf(a.x) | ((uint)f2bf(a.y) << 16);
  o.y = (uint)f2bf(a.z) | ((uint)f2bf(a.w) << 16);
  o.z = (uint)f2bf(b.x) | ((uint)f2bf(b.y) << 16);
  o.w = (uint)f2bf(b.z) | ((uint)f2bf(b.w) << 16);
  *(uint4*)&out[i] = o;
}

// ---------------------------------------------------------------------------
// Weight prep (N-major bf16)
// ---------------------------------------------------------------------------
__global__ __launch_bounds__(256) void prep_wt(const float* __restrict__ Wl1,
                                               const float* __restrict__ Wr1,
                                               const float* __restrict__ Wl2,
                                               const float* __restrict__ Wr2,
                                               ushort* __restrict__ WT1,
                                               ushort* __restrict__ WT2) {
  const int n = blockIdx.x;
  const int k = threadIdx.x;
  const float v1 = (k < 128) ? Wl1[k * 256 + n] : Wr1[(k - 128) * 256 + n];
  WT1[n * 256 + k] = f2bf(v1);
  const float v2 = (n < 128) ? Wl2[k * 128 + n] : Wr2[k * 128 + (n - 128)];
  WT2[n * 256 + k] = f2bf(v2);
}

// ---------------------------------------------------------------------------
// MFMA GEMM, layer 1: h = relu([aggb|xb] @ [Wl1;Wr1] + bl1), bf16 out.
// ---------------------------------------------------------------------------
__global__ __launch_bounds__(256) void gemm_l1(const ushort* __restrict__ aggb,
                                               const ushort* __restrict__ xb,
                                               const ushort* __restrict__ WT,
                                               const float* __restrict__ bias,
                                               ushort* __restrict__ h) {
  __shared__ ushort As[4096];
  __shared__ ushort Bs[4096];
  const int tid = threadIdx.x;
  const int w = tid >> 6;
  const int l = tid & 63;
  const int row0 = blockIdx.x * 128;
  const int col0 = blockIdx.y * 128;
  const int wm = (w >> 1) * 64;
  const int wn = (w & 1) * 64;
  const int srow = l >> 2;
  const int sbyte = (l & 3) * 16;
  f32x4 acc[4][4] = {};

  for (int kc = 0; kc < 8; ++kc) {
    const ushort* Ab = (kc < 4) ? aggb : xb;
    const int kco = (kc & 3) * 64;
    const int kbo = kc * 64;
    __syncthreads();
#pragma unroll
    for (int i = 0; i < 4; ++i) {
      const int c = w * 4 + i;
      if (c < 8) {
        int gr = row0 + c * 16 + srow;
        gr = (gr < N_NODES) ? gr : (N_NODES - 1);
        async_copy16((const char*)Ab + (size_t)gr * 256 + kco + sbyte,
                     (char*)As + c * 1024);
      } else {
        const int cb = c - 8;
        const int nr = col0 + cb * 16 + srow;
        async_copy16((const char*)WT + (size_t)nr * 512 + kbo + sbyte,
                     (char*)Bs + cb * 1024);
      }
    }
    __syncthreads();
    const int fr = l & 15;
    const int kg = (l >> 4) * 8;
    bf16x8 af[4], bfr[4];
#pragma unroll
    for (int i = 0; i < 4; ++i)
      af[i] = *(const bf16x8*)&As[(wm + i * 16 + fr) * 32 + kg];
#pragma unroll
    for (int j = 0; j < 4; ++j)
      bfr[j] = *(const bf16x8*)&Bs[(wn + j * 16 + fr) * 32 + kg];
#pragma unroll
    for (int i = 0; i < 4; ++i)
#pragma unroll
      for (int j = 0; j < 4; ++j)
        acc[i][j] = __builtin_amdgcn_mfma_f32_16x16x32_bf16(af[i], bfr[j],
                                                            acc[i][j], 0, 0, 0);
  }

  const int cr = (l >> 4) * 4;
  const int cc = l & 15;
#pragma unroll
  for (int i = 0; i < 4; ++i) {
    const int growb = row0 + wm + i * 16 + cr;
#pragma unroll
    for (int j = 0; j < 4; ++j) {
      const int gcol = col0 + wn + j * 16 + cc;
      const float bv = bias[gcol];
#pragma unroll
      for (int r = 0; r < 4; ++r) {
        const int grow = growb + r;
        if (grow < N_NODES) {
          const float v = fmaxf(acc[i][j][r] + bv, 0.f);
          h[(size_t)grow * 256 + gcol] = f2bf(v);
        }
      }
    }
  }
}

// ---------------------------------------------------------------------------
// MFMA GEMM, layer 2 fused: y==0 -> p = h@Wl2 (bf16); y==1 -> zp = h@Wr2+bl2.
// ---------------------------------------------------------------------------
__global__ __launch_bounds__(256) void gemm_l2(const ushort* __restrict__ h,
                                               const ushort* __restrict__ WT,
                                               const float* __restrict__ bias,
                                               ushort* __restrict__ p,
                                               float* __restrict__ zp) {
  __shared__ ushort As[4096];
  __shared__ ushort Bs[4096];
  const int tid = threadIdx.x;
  const int w = tid >> 6;
  const int l = tid & 63;
  const int row0 = blockIdx.x * 128;
  const int col0 = blockIdx.y * 128;
  const int wm = (w >> 1) * 64;
  const int wn = (w & 1) * 64;
  const int srow = l >> 2;
  const int sbyte = (l & 3) * 16;
  f32x4 acc[4][4] = {};

  for (int kc = 0; kc < 8; ++kc) {
    const int kbo = kc * 64;
    __syncthreads();
#pragma unroll
    for (int i = 0; i < 4; ++i) {
      const int c = w * 4 + i;
      if (c < 8) {
        int gr = row0 + c * 16 + srow;
        gr = (gr < N_NODES) ? gr : (N_NODES - 1);
        async_copy16((const char*)h + (size_t)gr * 512 + kbo + sbyte,
                     (char*)As + c * 1024);
      } else {
        const int cb = c - 8;
        const int nr = col0 + cb * 16 + srow;
        async_copy16((const char*)WT + (size_t)nr * 512 + kbo + sbyte,
                     (char*)Bs + cb * 1024);
      }
    }
    __syncthreads();
    const int fr = l & 15;
    const int kg = (l >> 4) * 8;
    bf16x8 af[4], bfr[4];
#pragma unroll
    for (int i = 0; i < 4; ++i)
      af[i] = *(const bf16x8*)&As[(wm + i * 16 + fr) * 32 + kg];
#pragma unroll
    for (int j = 0; j < 4; ++j)
      bfr[j] = *(const bf16x8*)&Bs[(wn + j * 16 + fr) * 32 + kg];
#pragma unroll
    for (int i = 0; i < 4; ++i)
#pragma unroll
      for (int j = 0; j < 4; ++j)
        acc[i][j] = __builtin_amdgcn_mfma_f32_16x16x32_bf16(af[i], bfr[j],
                                                            acc[i][j], 0, 0, 0);
  }

  const int cr = (l >> 4) * 4;
  const int cc = l & 15;
  const bool is_p = (blockIdx.y == 0);
#pragma unroll
  for (int i = 0; i < 4; ++i) {
    const int growb = row0 + wm + i * 16 + cr;
#pragma unroll
    for (int j = 0; j < 4; ++j) {
      const int gcl = wn + j * 16 + cc;
      const float bv = is_p ? 0.f : bias[gcl];
#pragma unroll
      for (int r = 0; r < 4; ++r) {
        const int grow = growb + r;
        if (grow < N_NODES) {
          const float v = acc[i][j][r] + bv;
          if (is_p)
            p[(size_t)grow * 128 + gcl] = f2bf(v);
          else
            zp[(size_t)grow * 128 + gcl] = v;
        }
      }
    }
  }
}

// ---------------------------------------------------------------------------
// Decode
// ---------------------------------------------------------------------------
__global__ __launch_bounds__(256) void dot_kernel(const int* __restrict__ ls,
                                                  const int* __restrict__ ld,
                                                  const float* __restrict__ z,
                                                  float* __restrict__ out) {
  long long tid = (long long)blockIdx.x * 256 + threadIdx.x;
  int e = (int)(tid >> 5);
  int lane = (int)(tid & 31);
  if (e >= N_LABEL) return;
  int a = ls[e], b = ld[e];
  const float4 va = *(const float4*)&z[(size_t)a * 128 + lane * 4];
  const float4 vb = *(const float4*)&z[(size_t)b * 128 + lane * 4];
  float p = va.x * vb.x + va.y * vb.y + va.z * vb.z + va.w * vb.w;
  p += __shfl_xor(p, 16, 32);
  p += __shfl_xor(p, 8, 32);
  p += __shfl_xor(p, 4, 32);
  p += __shfl_xor(p, 2, 32);
  p += __shfl_xor(p, 1, 32);
  if (lane == 0) out[e] = p;
}

extern "C" void kernel_launch(void* const* d_in, const int* in_sizes, int n_in,
                              void* d_out, int out_size, void* d_ws, size_t ws_size,
                              hipStream_t stream) {
  const float* x = (const float*)d_in[0];
  const int* ei = (const int*)d_in[1];
  const int* eli = (const int*)d_in[2];
  const float* Wl1 = (const float*)d_in[3];
  const float* bl1 = (const float*)d_in[4];
  const float* Wr1 = (const float*)d_in[5];
  const float* Wl2 = (const float*)d_in[6];
  const float* bl2 = (const float*)d_in[7];
  const float* Wr2 = (const float*)d_in[8];
  float* out = (float*)d_out;

  const int* e_src = ei;
  const int* e_dst = ei + N_EDGES;
  const int* l_src = eli;
  const int* l_dst = eli + N_LABEL;

  char* ws = (char*)d_ws;
  ushort* xb = (ushort*)(ws + 0);           //  25.6 MB
  ushort* aggb = (ushort*)(ws + 25600000);  //  25.6 MB
  ushort* h = (ushort*)(ws + 51200000);     //  51.2 MB
  ushort* p = (ushort*)(ws + 102400000);    //  25.6 MB
  float* z = (float*)(ws + 128000000);      //  51.2 MB
  ushort* WT1 = (ushort*)(ws + 179200000);  // 128 KB
  ushort* WT2 = (ushort*)(ws + 179331072);  // 128 KB
  uint* tmp = (uint*)(ws + 179462144);      // 6.4 MB packed edges
  int* cnt = (int*)(ws + 185862144);        // (FLEN+1) ints
  int* bsum = (int*)(ws + 186270000);       // 128 ints
  int* bpre = bsum + 128;                   // 128 ints

  const int SBLK = (FLEN + 1023) / 1024;  // 98

  // --- multisplit by dst>>6 (atomic-free, deterministic) ---
  bucket_count<<<NBF, 256, 0, stream>>>(e_dst, cnt);
  scan_sums<FLEN><<<SBLK, 256, 0, stream>>>(cnt, bsum);
  scan_tops<<<1, 128, 0, stream>>>(bsum, bpre, &cnt[FLEN], SBLK);
  scan_apply<FLEN><<<SBLK, 256, 0, stream>>>(cnt, bpre);
  bucket_fill<<<NBF, 256, 0, stream>>>(e_src, e_dst, cnt, tmp);

  // --- casts / weight prep ---
  cast_bf16<<<(N_NODES * C_IN) / (256 * 8), 256, 0, stream>>>(x, xb);
  prep_wt<<<256, 256, 0, stream>>>(Wl1, Wr1, Wl2, Wr2, WT1, WT2);

  // --- layer 1 ---
  agg_bucket<0><<<NBUCK, 256, 0, stream>>>(cnt, tmp, xb, aggb, nullptr);
  gemm_l1<<<dim3((N_NODES + 127) / 128, 2), 256, 0, stream>>>(aggb, xb, WT1, bl1, h);

  // --- layer 2 ---
  gemm_l2<<<dim3((N_NODES + 127) / 128, 2), 256, 0, stream>>>(h, WT2, bl2, p, z);
  agg_bucket<1><<<NBUCK, 256, 0, stream>>>(cnt, tmp, p, nullptr, z);

  // --- decode ---
  dot_kernel<<<(int)(((long long)N_LABEL * 32) / 256), 256, 0, stream>>>(
      l_src, l_dst, z, out);
}

// Round 7
// 456.747 us; speedup vs baseline: 5.6479x; 5.6479x over previous
//
#include <hip/hip_runtime.h>

#define N_NODES 100000
#define N_EDGES 1600000
#define N_LABEL 200000
#define C_IN 128
#define C_HID 256
#define C_OUT 128

#define BCHUNK 64                                 // nodes per bucket
#define NBUCK ((N_NODES + BCHUNK - 1) / BCHUNK)   // 1563
#define NBF 64                                    // multisplit blocks
#define EPB (N_EDGES / NBF)                       // 25000 edges per block
#define FLEN (NBUCK * NBF)                        // 100032 (bucket-major counts)
#define ESTORE 2048                               // max edges per bucket (mean 1024, sd 32)

typedef __attribute__((ext_vector_type(8))) short bf16x8;
typedef __attribute__((ext_vector_type(4))) float f32x4;

__device__ __forceinline__ ushort f2bf(float f) {  // RTNE
  uint u = __float_as_uint(f);
  return (ushort)((u + 0x7fffu + ((u >> 16) & 1u)) >> 16);
}

__device__ __forceinline__ void async_copy16(const void* g, void* lds) {
  __builtin_amdgcn_global_load_lds((const __attribute__((address_space(1))) void*)g,
                                   (__attribute__((address_space(3))) void*)lds,
                                   16, 0, 0);
}

// ---------------------------------------------------------------------------
// Multisplit P1: per-(block,bucket) histogram in LDS (chains ~16).
// cnt layout: [bucket][block]  (bucket-major).
// ---------------------------------------------------------------------------
__global__ __launch_bounds__(256) void bucket_count(const int* __restrict__ dst,
                                                    int* __restrict__ cnt) {
  __shared__ int lcnt[NBUCK];
  const int t = threadIdx.x;
  const int base = blockIdx.x * EPB;
  for (int b = t; b < NBUCK; b += 256) lcnt[b] = 0;
  __syncthreads();
  for (int i = t; i < EPB; i += 256) {
    atomicAdd(&lcnt[dst[base + i] >> 6], 1);
  }
  __syncthreads();
  for (int b = t; b < NBUCK; b += 256) cnt[b * NBF + blockIdx.x] = lcnt[b];
}

// ---------------------------------------------------------------------------
// 3-phase exclusive scan over cnt (length FLEN), in place.
// ---------------------------------------------------------------------------
template <int LEN>
__global__ __launch_bounds__(256) void scan_sums(const int* __restrict__ a,
                                                 int* __restrict__ bsum) {
  __shared__ int red[256];
  const int t = threadIdx.x;
  const int idx = blockIdx.x * 1024 + t * 4;
  int s = 0;
  if (idx + 3 < LEN) {
    const int4 v = *(const int4*)&a[idx];
    s = v.x + v.y + v.z + v.w;
  } else {
    for (int j = 0; j < 4 && idx + j < LEN; ++j) s += a[idx + j];
  }
  red[t] = s;
  __syncthreads();
  for (int off = 128; off > 0; off >>= 1) {
    if (t < off) red[t] += red[t + off];
    __syncthreads();
  }
  if (t == 0) bsum[blockIdx.x] = red[0];
}

__global__ __launch_bounds__(128) void scan_tops(const int* __restrict__ bsum,
                                                 int* __restrict__ bpre,
                                                 int* __restrict__ total, int nb) {
  __shared__ int sh[128];
  const int t = threadIdx.x;
  sh[t] = (t < nb) ? bsum[t] : 0;
  __syncthreads();
  for (int off = 1; off < 128; off <<= 1) {
    int v = 0;
    if (t >= off) v = sh[t - off];
    __syncthreads();
    if (t >= off) sh[t] += v;
    __syncthreads();
  }
  if (t < nb) bpre[t] = (t == 0) ? 0 : sh[t - 1];
  if (t == nb - 1) *total = sh[t];
}

template <int LEN>
__global__ __launch_bounds__(256) void scan_apply(int* __restrict__ a,
                                                  const int* __restrict__ bpre) {
  __shared__ int sh[256];
  const int t = threadIdx.x;
  const int idx = blockIdx.x * 1024 + t * 4;
  int4 v = make_int4(0, 0, 0, 0);
  const bool full = (idx + 3 < LEN);
  if (full) {
    v = *(const int4*)&a[idx];
  } else {
    if (idx + 0 < LEN) v.x = a[idx + 0];
    if (idx + 1 < LEN) v.y = a[idx + 1];
    if (idx + 2 < LEN) v.z = a[idx + 2];
    if (idx + 3 < LEN) v.w = a[idx + 3];
  }
  sh[t] = v.x + v.y + v.z + v.w;
  __syncthreads();
  for (int off = 1; off < 256; off <<= 1) {
    int u = 0;
    if (t >= off) u = sh[t - off];
    __syncthreads();
    if (t >= off) sh[t] += u;
    __syncthreads();
  }
  const int base = bpre[blockIdx.x] + ((t == 0) ? 0 : sh[t - 1]);
  int4 e;
  e.x = base;
  e.y = base + v.x;
  e.z = base + v.x + v.y;
  e.w = base + v.x + v.y + v.z;
  if (full) {
    *(int4*)&a[idx] = e;
  } else {
    if (idx + 0 < LEN) a[idx + 0] = e.x;
    if (idx + 1 < LEN) a[idx + 1] = e.y;
    if (idx + 2 < LEN) a[idx + 2] = e.z;
    if (idx + 3 < LEN) a[idx + 3] = e.w;
  }
}

// ---------------------------------------------------------------------------
// Multisplit P3: deterministic bucket scatter with LDS cursors (no global
// atomics). Entry = (src<<6)|(dst&63).
// ---------------------------------------------------------------------------
__global__ __launch_bounds__(256) void bucket_fill(const int* __restrict__ src,
                                                   const int* __restrict__ dst,
                                                   const int* __restrict__ cnt,
                                                   uint* __restrict__ tmp) {
  __shared__ int lcur[NBUCK];
  const int t = threadIdx.x;
  const int base = blockIdx.x * EPB;
  for (int b = t; b < NBUCK; b += 256) lcur[b] = cnt[b * NBF + blockIdx.x];
  __syncthreads();
  for (int i = t; i < EPB; i += 256) {
    const int d = dst[base + i];
    const int s = src[base + i];
    const int pos = atomicAdd(&lcur[d >> 6], 1);
    tmp[pos] = ((uint)s << 6) | (uint)(d & 63);
  }
}

// ---------------------------------------------------------------------------
// Per-bucket CSR finalize, fully in LDS, single pass over tmp:
// load bucket entries -> count per node -> 64-wide scan (writes row_start) ->
// LDS counting-sort scatter -> coalesced write back IN PLACE over tmp
// (tmp becomes csr_src: per-node contiguous source lists).
// Bucket size ~1024 +- 32 (binomial); ESTORE=2048 is ~32 sigma headroom.
// ---------------------------------------------------------------------------
__global__ __launch_bounds__(256) void csr_build(const int* __restrict__ cnt,
                                                 uint* __restrict__ tmp,
                                                 int* __restrict__ row_start) {
  __shared__ uint est[ESTORE];
  __shared__ uint eso[ESTORE];
  __shared__ int lcnt[BCHUNK];
  __shared__ int lcur[BCHUNK];
  const int b = blockIdx.x;
  const int t = threadIdx.x;
  const int s = cnt[b * NBF];
  const int e = cnt[(b + 1) * NBF];  // b==NBUCK-1 -> cnt[FLEN] == N_EDGES
  const int n = e - s;
  for (int j = t; j < n; j += 256) est[j] = tmp[s + j];
  if (t < BCHUNK) lcnt[t] = 0;
  __syncthreads();
  for (int j = t; j < n; j += 256) atomicAdd(&lcnt[est[j] & 63], 1);
  __syncthreads();
  // Hillis-Steele inclusive scan over the 64 counters
  for (int off = 1; off < BCHUNK; off <<= 1) {
    int v = 0;
    if (t >= off && t < BCHUNK) v = lcnt[t - off];
    __syncthreads();
    if (t >= off && t < BCHUNK) lcnt[t] += v;
    __syncthreads();
  }
  if (t < BCHUNK) {
    const int ex = (t == 0) ? 0 : lcnt[t - 1];
    lcur[t] = ex;
    const int node = b * BCHUNK + t;
    if (node < N_NODES) row_start[node] = s + ex;
  }
  if (b == NBUCK - 1 && t == 0) row_start[N_NODES] = e;
  __syncthreads();
  for (int j = t; j < n; j += 256) {
    const uint v = est[j];
    const int pos = atomicAdd(&lcur[v & 63], 1);
    eso[pos] = v >> 6;
  }
  __syncthreads();
  for (int j = t; j < n; j += 256) tmp[s + j] = eso[j];  // coalesced
}

// ---------------------------------------------------------------------------
// fp32 -> bf16 cast (8 elems / thread)
// ---------------------------------------------------------------------------
__global__ __launch_bounds__(256) void cast_bf16(const float* __restrict__ in,
                                                 ushort* __restrict__ out) {
  const size_t i = ((size_t)blockIdx.x * 256 + threadIdx.x) * 8;
  const float4 a = *(const float4*)&in[i];
  const float4 b = *(const float4*)&in[i + 4];
  uint4 o;
  o.x = (uint)f2bf(a.x) | ((uint)f2bf(a.y) << 16);
  o.y = (uint)f2bf(a.z) | ((uint)f2bf(a.w) << 16);
  o.z = (uint)f2bf(b.x) | ((uint)f2bf(b.y) << 16);
  o.w = (uint)f2bf(b.z) | ((uint)f2bf(b.w) << 16);
  *(uint4*)&out[i] = o;
}

// ---------------------------------------------------------------------------
// Weight prep (N-major bf16)
// ---------------------------------------------------------------------------
__global__ __launch_bounds__(256) void prep_wt(const float* __restrict__ Wl1,
                                               const float* __restrict__ Wr1,
                                               const float* __restrict__ Wl2,
                                               const float* __restrict__ Wr2,
                                               ushort* __restrict__ WT1,
                                               ushort* __restrict__ WT2) {
  const int n = blockIdx.x;
  const int k = threadIdx.x;
  const float v1 = (k < 128) ? Wl1[k * 256 + n] : Wr1[(k - 128) * 256 + n];
  WT1[n * 256 + k] = f2bf(v1);
  const float v2 = (n < 128) ? Wl2[k * 128 + n] : Wr2[k * 128 + (n - 128)];
  WT2[n * 256 + k] = f2bf(v2);
}

// ---------------------------------------------------------------------------
// Mean aggregation by register gather over bf16 rows, fp32 accumulate.
// One 64-lane wave per node (float2/lane = 256B coalesced row read).
// MODE 0: write bf16 mean.  MODE 1: z[node] += mean (fp32, in place).
// ---------------------------------------------------------------------------
template <int MODE>
__global__ __launch_bounds__(256) void gather_mean_b(const int* __restrict__ row_start,
                                                     const uint* __restrict__ csr_src,
                                                     const ushort* __restrict__ feat,
                                                     ushort* __restrict__ bout,
                                                     float* __restrict__ z) {
  const int wid = blockIdx.x * 4 + (threadIdx.x >> 6);
  const int lane = threadIdx.x & 63;
  if (wid >= N_NODES) return;
  const int s = row_start[wid];
  const int e = row_start[wid + 1];
  const int c0 = lane * 2;
  float a0 = 0.f, a1 = 0.f, b0 = 0.f, b1 = 0.f;
  int j = s;
  for (; j + 1 < e; j += 2) {
    const uint v0 = *(const uint*)&feat[(size_t)csr_src[j] * 128 + c0];
    const uint v1 = *(const uint*)&feat[(size_t)csr_src[j + 1] * 128 + c0];
    a0 += __uint_as_float(v0 << 16);
    a1 += __uint_as_float(v0 & 0xffff0000u);
    b0 += __uint_as_float(v1 << 16);
    b1 += __uint_as_float(v1 & 0xffff0000u);
  }
  if (j < e) {
    const uint v0 = *(const uint*)&feat[(size_t)csr_src[j] * 128 + c0];
    a0 += __uint_as_float(v0 << 16);
    a1 += __uint_as_float(v0 & 0xffff0000u);
  }
  const float rd = 1.0f / fmaxf((float)(e - s), 1.0f);
  const float m0 = (a0 + b0) * rd;
  const float m1 = (a1 + b1) * rd;
  if (MODE == 0) {
    *(uint*)&bout[(size_t)wid * 128 + c0] = (uint)f2bf(m0) | ((uint)f2bf(m1) << 16);
  } else {
    float2 zv = *(const float2*)&z[(size_t)wid * 128 + c0];
    zv.x += m0;
    zv.y += m1;
    *(float2*)&z[(size_t)wid * 128 + c0] = zv;
  }
}

// ---------------------------------------------------------------------------
// MFMA GEMM, layer 1: h = relu([aggb|xb] @ [Wl1;Wr1] + bl1), bf16 out.
// 128x128 tile, 4 waves, BK=32, mfma_f32_16x16x32_bf16, global_load_lds.
// ---------------------------------------------------------------------------
__global__ __launch_bounds__(256) void gemm_l1(const ushort* __restrict__ aggb,
                                               const ushort* __restrict__ xb,
                                               const ushort* __restrict__ WT,
                                               const float* __restrict__ bias,
                                               ushort* __restrict__ h) {
  __shared__ ushort As[4096];
  __shared__ ushort Bs[4096];
  const int tid = threadIdx.x;
  const int w = tid >> 6;
  const int l = tid & 63;
  const int row0 = blockIdx.x * 128;
  const int col0 = blockIdx.y * 128;
  const int wm = (w >> 1) * 64;
  const int wn = (w & 1) * 64;
  const int srow = l >> 2;
  const int sbyte = (l & 3) * 16;
  f32x4 acc[4][4] = {};

  for (int kc = 0; kc < 8; ++kc) {
    const ushort* Ab = (kc < 4) ? aggb : xb;
    const int kco = (kc & 3) * 64;
    const int kbo = kc * 64;
    __syncthreads();
#pragma unroll
    for (int i = 0; i < 4; ++i) {
      const int c = w * 4 + i;
      if (c < 8) {
        int gr = row0 + c * 16 + srow;
        gr = (gr < N_NODES) ? gr : (N_NODES - 1);
        async_copy16((const char*)Ab + (size_t)gr * 256 + kco + sbyte,
                     (char*)As + c * 1024);
      } else {
        const int cb = c - 8;
        const int nr = col0 + cb * 16 + srow;
        async_copy16((const char*)WT + (size_t)nr * 512 + kbo + sbyte,
                     (char*)Bs + cb * 1024);
      }
    }
    __syncthreads();
    const int fr = l & 15;
    const int kg = (l >> 4) * 8;
    bf16x8 af[4], bfr[4];
#pragma unroll
    for (int i = 0; i < 4; ++i)
      af[i] = *(const bf16x8*)&As[(wm + i * 16 + fr) * 32 + kg];
#pragma unroll
    for (int j = 0; j < 4; ++j)
      bfr[j] = *(const bf16x8*)&Bs[(wn + j * 16 + fr) * 32 + kg];
#pragma unroll
    for (int i = 0; i < 4; ++i)
#pragma unroll
      for (int j = 0; j < 4; ++j)
        acc[i][j] = __builtin_amdgcn_mfma_f32_16x16x32_bf16(af[i], bfr[j],
                                                            acc[i][j], 0, 0, 0);
  }

  const int cr = (l >> 4) * 4;
  const int cc = l & 15;
#pragma unroll
  for (int i = 0; i < 4; ++i) {
    const int growb = row0 + wm + i * 16 + cr;
#pragma unroll
    for (int j = 0; j < 4; ++j) {
      const int gcol = col0 + wn + j * 16 + cc;
      const float bv = bias[gcol];
#pragma unroll
      for (int r = 0; r < 4; ++r) {
        const int grow = growb + r;
        if (grow < N_NODES) {
          const float v = fmaxf(acc[i][j][r] + bv, 0.f);
          h[(size_t)grow * 256 + gcol] = f2bf(v);
        }
      }
    }
  }
}

// ---------------------------------------------------------------------------
// MFMA GEMM, layer 2 fused: y==0 -> p = h@Wl2 (bf16); y==1 -> zp = h@Wr2+bl2.
// ---------------------------------------------------------------------------
__global__ __launch_bounds__(256) void gemm_l2(const ushort* __restrict__ h,
                                               const ushort* __restrict__ WT,
                                               const float* __restrict__ bias,
                                               ushort* __restrict__ p,
                                               float* __restrict__ zp) {
  __shared__ ushort As[4096];
  __shared__ ushort Bs[4096];
  const int tid = threadIdx.x;
  const int w = tid >> 6;
  const int l = tid & 63;
  const int row0 = blockIdx.x * 128;
  const int col0 = blockIdx.y * 128;
  const int wm = (w >> 1) * 64;
  const int wn = (w & 1) * 64;
  const int srow = l >> 2;
  const int sbyte = (l & 3) * 16;
  f32x4 acc[4][4] = {};

  for (int kc = 0; kc < 8; ++kc) {
    const int kbo = kc * 64;
    __syncthreads();
#pragma unroll
    for (int i = 0; i < 4; ++i) {
      const int c = w * 4 + i;
      if (c < 8) {
        int gr = row0 + c * 16 + srow;
        gr = (gr < N_NODES) ? gr : (N_NODES - 1);
        async_copy16((const char*)h + (size_t)gr * 512 + kbo + sbyte,
                     (char*)As + c * 1024);
      } else {
        const int cb = c - 8;
        const int nr = col0 + cb * 16 + srow;
        async_copy16((const char*)WT + (size_t)nr * 512 + kbo + sbyte,
                     (char*)Bs + cb * 1024);
      }
    }
    __syncthreads();
    const int fr = l & 15;
    const int kg = (l >> 4) * 8;
    bf16x8 af[4], bfr[4];
#pragma unroll
    for (int i = 0; i < 4; ++i)
      af[i] = *(const bf16x8*)&As[(wm + i * 16 + fr) * 32 + kg];
#pragma unroll
    for (int j = 0; j < 4; ++j)
      bfr[j] = *(const bf16x8*)&Bs[(wn + j * 16 + fr) * 32 + kg];
#pragma unroll
    for (int i = 0; i < 4; ++i)
#pragma unroll
      for (int j = 0; j < 4; ++j)
        acc[i][j] = __builtin_amdgcn_mfma_f32_16x16x32_bf16(af[i], bfr[j],
                                                            acc[i][j], 0, 0, 0);
  }

  const int cr = (l >> 4) * 4;
  const int cc = l & 15;
  const bool is_p = (blockIdx.y == 0);
#pragma unroll
  for (int i = 0; i < 4; ++i) {
    const int growb = row0 + wm + i * 16 + cr;
#pragma unroll
    for (int j = 0; j < 4; ++j) {
      const int gcl = wn + j * 16 + cc;
      const float bv = is_p ? 0.f : bias[gcl];
#pragma unroll
      for (int r = 0; r < 4; ++r) {
        const int grow = growb + r;
        if (grow < N_NODES) {
          const float v = acc[i][j][r] + bv;
          if (is_p)
            p[(size_t)grow * 128 + gcl] = f2bf(v);
          else
            zp[(size_t)grow * 128 + gcl] = v;
        }
      }
    }
  }
}

// ---------------------------------------------------------------------------
// Decode
// ---------------------------------------------------------------------------
__global__ __launch_bounds__(256) void dot_kernel(const int* __restrict__ ls,
                                                  const int* __restrict__ ld,
                                                  const float* __restrict__ z,
                                                  float* __restrict__ out) {
  long long tid = (long long)blockIdx.x * 256 + threadIdx.x;
  int e = (int)(tid >> 5);
  int lane = (int)(tid & 31);
  if (e >= N_LABEL) return;
  int a = ls[e], b = ld[e];
  const float4 va = *(const float4*)&z[(size_t)a * 128 + lane * 4];
  const float4 vb = *(const float4*)&z[(size_t)b * 128 + lane * 4];
  float p = va.x * vb.x + va.y * vb.y + va.z * vb.z + va.w * vb.w;
  p += __shfl_xor(p, 16, 32);
  p += __shfl_xor(p, 8, 32);
  p += __shfl_xor(p, 4, 32);
  p += __shfl_xor(p, 2, 32);
  p += __shfl_xor(p, 1, 32);
  if (lane == 0) out[e] = p;
}

extern "C" void kernel_launch(void* const* d_in, const int* in_sizes, int n_in,
                              void* d_out, int out_size, void* d_ws, size_t ws_size,
                              hipStream_t stream) {
  const float* x = (const float*)d_in[0];
  const int* ei = (const int*)d_in[1];
  const int* eli = (const int*)d_in[2];
  const float* Wl1 = (const float*)d_in[3];
  const float* bl1 = (const float*)d_in[4];
  const float* Wr1 = (const float*)d_in[5];
  const float* Wl2 = (const float*)d_in[6];
  const float* bl2 = (const float*)d_in[7];
  const float* Wr2 = (const float*)d_in[8];
  float* out = (float*)d_out;

  const int* e_src = ei;
  const int* e_dst = ei + N_EDGES;
  const int* l_src = eli;
  const int* l_dst = eli + N_LABEL;

  char* ws = (char*)d_ws;
  ushort* xb = (ushort*)(ws + 0);           //  25.6 MB
  ushort* aggb = (ushort*)(ws + 25600000);  //  25.6 MB
  ushort* h = (ushort*)(ws + 51200000);     //  51.2 MB
  ushort* p = (ushort*)(ws + 102400000);    //  25.6 MB
  float* z = (float*)(ws + 128000000);      //  51.2 MB
  ushort* WT1 = (ushort*)(ws + 179200000);  // 128 KB
  ushort* WT2 = (ushort*)(ws + 179331072);  // 128 KB
  uint* tmp = (uint*)(ws + 179462144);      // 6.4 MB packed edges -> csr_src
  int* cnt = (int*)(ws + 185862144);        // (FLEN+1) ints
  int* bsum = (int*)(ws + 186270000);       // 128 ints
  int* bpre = bsum + 128;                   // 128 ints
  int* row_start = (int*)(ws + 186280000);  // (N_NODES+1) ints

  const int SBLK = (FLEN + 1023) / 1024;  // 98

  // --- multisplit by dst>>6 + in-LDS per-bucket counting sort ---
  bucket_count<<<NBF, 256, 0, stream>>>(e_dst, cnt);
  scan_sums<FLEN><<<SBLK, 256, 0, stream>>>(cnt, bsum);
  scan_tops<<<1, 128, 0, stream>>>(bsum, bpre, &cnt[FLEN], SBLK);
  scan_apply<FLEN><<<SBLK, 256, 0, stream>>>(cnt, bpre);
  bucket_fill<<<NBF, 256, 0, stream>>>(e_src, e_dst, cnt, tmp);
  csr_build<<<NBUCK, 256, 0, stream>>>(cnt, tmp, row_start);

  // --- casts / weight prep ---
  cast_bf16<<<(N_NODES * C_IN) / (256 * 8), 256, 0, stream>>>(x, xb);
  prep_wt<<<256, 256, 0, stream>>>(Wl1, Wr1, Wl2, Wr2, WT1, WT2);

  // --- layer 1 ---
  gather_mean_b<0><<<(N_NODES + 3) / 4, 256, 0, stream>>>(row_start, tmp, xb,
                                                          aggb, nullptr);
  gemm_l1<<<dim3((N_NODES + 127) / 128, 2), 256, 0, stream>>>(aggb, xb, WT1, bl1, h);

  // --- layer 2 ---
  gemm_l2<<<dim3((N_NODES + 127) / 128, 2), 256, 0, stream>>>(h, WT2, bl2, p, z);
  gather_mean_b<1><<<(N_NODES + 3) / 4, 256, 0, stream>>>(row_start, tmp, p,
                                                          nullptr, z);

  // --- decode ---
  dot_kernel<<<(int)(((long long)N_LABEL * 32) / 256), 256, 0, stream>>>(
      l_src, l_dst, z, out);
}

// Round 8
// 369.364 us; speedup vs baseline: 6.9841x; 1.2366x over previous
//
#include <hip/hip_runtime.h>

#define N_NODES 100000
#define N_EDGES 1600000
#define N_LABEL 200000
#define C_IN 128
#define C_HID 256
#define C_OUT 128

#define BCHUNK 64                                 // nodes per bucket
#define NBUCK ((N_NODES + BCHUNK - 1) / BCHUNK)   // 1563
#define NBF 64                                    // multisplit blocks
#define EPB (N_EDGES / NBF)                       // 25000 edges per block
#define FLEN (NBUCK * NBF)                        // 100032 (bucket-major counts)
#define ESTORE 2048                               // max edges per bucket

typedef __attribute__((ext_vector_type(8))) short bf16x8;
typedef __attribute__((ext_vector_type(4))) float f32x4;

__device__ __forceinline__ ushort f2bf(float f) {  // RTNE
  uint u = __float_as_uint(f);
  return (ushort)((u + 0x7fffu + ((u >> 16) & 1u)) >> 16);
}

__device__ __forceinline__ float bfl(uint u) { return __uint_as_float(u << 16); }
__device__ __forceinline__ float bfh(uint u) {
  return __uint_as_float(u & 0xffff0000u);
}

__device__ __forceinline__ void async_copy16(const void* g, void* lds) {
  __builtin_amdgcn_global_load_lds((const __attribute__((address_space(1))) void*)g,
                                   (__attribute__((address_space(3))) void*)lds,
                                   16, 0, 0);
}

// ---------------------------------------------------------------------------
// Multisplit P1: per-(block,bucket) histogram in LDS (chains ~16).
// ---------------------------------------------------------------------------
__global__ __launch_bounds__(256) void bucket_count(const int* __restrict__ dst,
                                                    int* __restrict__ cnt) {
  __shared__ int lcnt[NBUCK];
  const int t = threadIdx.x;
  const int base = blockIdx.x * EPB;
  for (int b = t; b < NBUCK; b += 256) lcnt[b] = 0;
  __syncthreads();
  for (int i = t; i < EPB; i += 256) {
    atomicAdd(&lcnt[dst[base + i] >> 6], 1);
  }
  __syncthreads();
  for (int b = t; b < NBUCK; b += 256) cnt[b * NBF + blockIdx.x] = lcnt[b];
}

// ---------------------------------------------------------------------------
// 3-phase exclusive scan over cnt (length FLEN), in place.
// ---------------------------------------------------------------------------
template <int LEN>
__global__ __launch_bounds__(256) void scan_sums(const int* __restrict__ a,
                                                 int* __restrict__ bsum) {
  __shared__ int red[256];
  const int t = threadIdx.x;
  const int idx = blockIdx.x * 1024 + t * 4;
  int s = 0;
  if (idx + 3 < LEN) {
    const int4 v = *(const int4*)&a[idx];
    s = v.x + v.y + v.z + v.w;
  } else {
    for (int j = 0; j < 4 && idx + j < LEN; ++j) s += a[idx + j];
  }
  red[t] = s;
  __syncthreads();
  for (int off = 128; off > 0; off >>= 1) {
    if (t < off) red[t] += red[t + off];
    __syncthreads();
  }
  if (t == 0) bsum[blockIdx.x] = red[0];
}

__global__ __launch_bounds__(128) void scan_tops(const int* __restrict__ bsum,
                                                 int* __restrict__ bpre,
                                                 int* __restrict__ total, int nb) {
  __shared__ int sh[128];
  const int t = threadIdx.x;
  sh[t] = (t < nb) ? bsum[t] : 0;
  __syncthreads();
  for (int off = 1; off < 128; off <<= 1) {
    int v = 0;
    if (t >= off) v = sh[t - off];
    __syncthreads();
    if (t >= off) sh[t] += v;
    __syncthreads();
  }
  if (t < nb) bpre[t] = (t == 0) ? 0 : sh[t - 1];
  if (t == nb - 1) *total = sh[t];
}

template <int LEN>
__global__ __launch_bounds__(256) void scan_apply(int* __restrict__ a,
                                                  const int* __restrict__ bpre) {
  __shared__ int sh[256];
  const int t = threadIdx.x;
  const int idx = blockIdx.x * 1024 + t * 4;
  int4 v = make_int4(0, 0, 0, 0);
  const bool full = (idx + 3 < LEN);
  if (full) {
    v = *(const int4*)&a[idx];
  } else {
    if (idx + 0 < LEN) v.x = a[idx + 0];
    if (idx + 1 < LEN) v.y = a[idx + 1];
    if (idx + 2 < LEN) v.z = a[idx + 2];
    if (idx + 3 < LEN) v.w = a[idx + 3];
  }
  sh[t] = v.x + v.y + v.z + v.w;
  __syncthreads();
  for (int off = 1; off < 256; off <<= 1) {
    int u = 0;
    if (t >= off) u = sh[t - off];
    __syncthreads();
    if (t >= off) sh[t] += u;
    __syncthreads();
  }
  const int base = bpre[blockIdx.x] + ((t == 0) ? 0 : sh[t - 1]);
  int4 e;
  e.x = base;
  e.y = base + v.x;
  e.z = base + v.x + v.y;
  e.w = base + v.x + v.y + v.z;
  if (full) {
    *(int4*)&a[idx] = e;
  } else {
    if (idx + 0 < LEN) a[idx + 0] = e.x;
    if (idx + 1 < LEN) a[idx + 1] = e.y;
    if (idx + 2 < LEN) a[idx + 2] = e.z;
    if (idx + 3 < LEN) a[idx + 3] = e.w;
  }
}

// ---------------------------------------------------------------------------
// Multisplit P3: deterministic bucket scatter with LDS cursors.
// ---------------------------------------------------------------------------
__global__ __launch_bounds__(256) void bucket_fill(const int* __restrict__ src,
                                                   const int* __restrict__ dst,
                                                   const int* __restrict__ cnt,
                                                   uint* __restrict__ tmp) {
  __shared__ int lcur[NBUCK];
  const int t = threadIdx.x;
  const int base = blockIdx.x * EPB;
  for (int b = t; b < NBUCK; b += 256) lcur[b] = cnt[b * NBF + blockIdx.x];
  __syncthreads();
  for (int i = t; i < EPB; i += 256) {
    const int d = dst[base + i];
    const int s = src[base + i];
    const int pos = atomicAdd(&lcur[d >> 6], 1);
    tmp[pos] = ((uint)s << 6) | (uint)(d & 63);
  }
}

// ---------------------------------------------------------------------------
// Per-bucket CSR finalize, in LDS; tmp becomes csr_src in place.
// ---------------------------------------------------------------------------
__global__ __launch_bounds__(256) void csr_build(const int* __restrict__ cnt,
                                                 uint* __restrict__ tmp,
                                                 int* __restrict__ row_start) {
  __shared__ uint est[ESTORE];
  __shared__ uint eso[ESTORE];
  __shared__ int lcnt[BCHUNK];
  __shared__ int lcur[BCHUNK];
  const int b = blockIdx.x;
  const int t = threadIdx.x;
  const int s = cnt[b * NBF];
  const int e = cnt[(b + 1) * NBF];
  const int n = e - s;
  for (int j = t; j < n; j += 256) est[j] = tmp[s + j];
  if (t < BCHUNK) lcnt[t] = 0;
  __syncthreads();
  for (int j = t; j < n; j += 256) atomicAdd(&lcnt[est[j] & 63], 1);
  __syncthreads();
  for (int off = 1; off < BCHUNK; off <<= 1) {
    int v = 0;
    if (t >= off && t < BCHUNK) v = lcnt[t - off];
    __syncthreads();
    if (t >= off && t < BCHUNK) lcnt[t] += v;
    __syncthreads();
  }
  if (t < BCHUNK) {
    const int ex = (t == 0) ? 0 : lcnt[t - 1];
    lcur[t] = ex;
    const int node = b * BCHUNK + t;
    if (node < N_NODES) row_start[node] = s + ex;
  }
  if (b == NBUCK - 1 && t == 0) row_start[N_NODES] = e;
  __syncthreads();
  for (int j = t; j < n; j += 256) {
    const uint v = est[j];
    const int pos = atomicAdd(&lcur[v & 63], 1);
    eso[pos] = v >> 6;
  }
  __syncthreads();
  for (int j = t; j < n; j += 256) tmp[s + j] = eso[j];
}

// ---------------------------------------------------------------------------
// fp32 -> bf16 cast (8 elems / thread)
// ---------------------------------------------------------------------------
__global__ __launch_bounds__(256) void cast_bf16(const float* __restrict__ in,
                                                 ushort* __restrict__ out) {
  const size_t i = ((size_t)blockIdx.x * 256 + threadIdx.x) * 8;
  const float4 a = *(const float4*)&in[i];
  const float4 b = *(const float4*)&in[i + 4];
  uint4 o;
  o.x = (uint)f2bf(a.x) | ((uint)f2bf(a.y) << 16);
  o.y = (uint)f2bf(a.z) | ((uint)f2bf(a.w) << 16);
  o.z = (uint)f2bf(b.x) | ((uint)f2bf(b.y) << 16);
  o.w = (uint)f2bf(b.z) | ((uint)f2bf(b.w) << 16);
  *(uint4*)&out[i] = o;
}

// ---------------------------------------------------------------------------
// Weight prep (N-major bf16)
// ---------------------------------------------------------------------------
__global__ __launch_bounds__(256) void prep_wt(const float* __restrict__ Wl1,
                                               const float* __restrict__ Wr1,
                                               const float* __restrict__ Wl2,
                                               const float* __restrict__ Wr2,
                                               ushort* __restrict__ WT1,
                                               ushort* __restrict__ WT2) {
  const int n = blockIdx.x;
  const int k = threadIdx.x;
  const float v1 = (k < 128) ? Wl1[k * 256 + n] : Wr1[(k - 128) * 256 + n];
  WT1[n * 256 + k] = f2bf(v1);
  const float v2 = (n < 128) ? Wl2[k * 128 + n] : Wr2[k * 128 + (n - 128)];
  WT2[n * 256 + k] = f2bf(v2);
}

// ---------------------------------------------------------------------------
// Mean aggregation: one wave per node; 4 edge-slots x 16 lanes x bf16x8
// (16B/lane) => one dwordx4 instruction fetches 4 independent 256B rows.
// Unroll 2 -> 8 rows in flight per wave. Cross-slot shfl_xor reduce at end.
// MODE 0: write bf16 mean.  MODE 1: z[node] += mean (fp32, in place).
// ---------------------------------------------------------------------------
template <int MODE>
__global__ __launch_bounds__(256) void gather_mean_b(const int* __restrict__ row_start,
                                                     const uint* __restrict__ csr_src,
                                                     const ushort* __restrict__ feat,
                                                     ushort* __restrict__ bout,
                                                     float* __restrict__ z) {
  const int wid = blockIdx.x * 4 + (threadIdx.x >> 6);
  const int lane = threadIdx.x & 63;
  if (wid >= N_NODES) return;
  const int s = row_start[wid];
  const int e = row_start[wid + 1];
  const int slot = lane >> 4;
  const int c0 = (lane & 15) * 8;
  float acc[8] = {};
  int j = s + slot;
  for (; j + 4 < e; j += 8) {
    const uint s0 = csr_src[j];
    const uint s1 = csr_src[j + 4];
    const uint4 r0 = *(const uint4*)&feat[(size_t)s0 * 128 + c0];
    const uint4 r1 = *(const uint4*)&feat[(size_t)s1 * 128 + c0];
    acc[0] += bfl(r0.x); acc[1] += bfh(r0.x);
    acc[2] += bfl(r0.y); acc[3] += bfh(r0.y);
    acc[4] += bfl(r0.z); acc[5] += bfh(r0.z);
    acc[6] += bfl(r0.w); acc[7] += bfh(r0.w);
    acc[0] += bfl(r1.x); acc[1] += bfh(r1.x);
    acc[2] += bfl(r1.y); acc[3] += bfh(r1.y);
    acc[4] += bfl(r1.z); acc[5] += bfh(r1.z);
    acc[6] += bfl(r1.w); acc[7] += bfh(r1.w);
  }
  if (j < e) {
    const uint s0 = csr_src[j];
    const uint4 r0 = *(const uint4*)&feat[(size_t)s0 * 128 + c0];
    acc[0] += bfl(r0.x); acc[1] += bfh(r0.x);
    acc[2] += bfl(r0.y); acc[3] += bfh(r0.y);
    acc[4] += bfl(r0.z); acc[5] += bfh(r0.z);
    acc[6] += bfl(r0.w); acc[7] += bfh(r0.w);
  }
#pragma unroll
  for (int k = 0; k < 8; ++k) {
    acc[k] += __shfl_xor(acc[k], 16, 64);
    acc[k] += __shfl_xor(acc[k], 32, 64);
  }
  if (slot == 0) {
    const float rd = 1.0f / fmaxf((float)(e - s), 1.0f);
    if (MODE == 0) {
      uint4 o;
      o.x = (uint)f2bf(acc[0] * rd) | ((uint)f2bf(acc[1] * rd) << 16);
      o.y = (uint)f2bf(acc[2] * rd) | ((uint)f2bf(acc[3] * rd) << 16);
      o.z = (uint)f2bf(acc[4] * rd) | ((uint)f2bf(acc[5] * rd) << 16);
      o.w = (uint)f2bf(acc[6] * rd) | ((uint)f2bf(acc[7] * rd) << 16);
      *(uint4*)&bout[(size_t)wid * 128 + c0] = o;
    } else {
      float4 z0 = *(const float4*)&z[(size_t)wid * 128 + c0];
      float4 z1 = *(const float4*)&z[(size_t)wid * 128 + c0 + 4];
      z0.x += acc[0] * rd; z0.y += acc[1] * rd;
      z0.z += acc[2] * rd; z0.w += acc[3] * rd;
      z1.x += acc[4] * rd; z1.y += acc[5] * rd;
      z1.z += acc[6] * rd; z1.w += acc[7] * rd;
      *(float4*)&z[(size_t)wid * 128 + c0] = z0;
      *(float4*)&z[(size_t)wid * 128 + c0 + 4] = z1;
    }
  }
}

// ---------------------------------------------------------------------------
// MFMA GEMM, layer 1: h = relu([aggb|xb] @ [Wl1;Wr1] + bl1), bf16 out.
// ---------------------------------------------------------------------------
__global__ __launch_bounds__(256) void gemm_l1(const ushort* __restrict__ aggb,
                                               const ushort* __restrict__ xb,
                                               const ushort* __restrict__ WT,
                                               const float* __restrict__ bias,
                                               ushort* __restrict__ h) {
  __shared__ ushort As[4096];
  __shared__ ushort Bs[4096];
  const int tid = threadIdx.x;
  const int w = tid >> 6;
  const int l = tid & 63;
  const int row0 = blockIdx.x * 128;
  const int col0 = blockIdx.y * 128;
  const int wm = (w >> 1) * 64;
  const int wn = (w & 1) * 64;
  const int srow = l >> 2;
  const int sbyte = (l & 3) * 16;
  f32x4 acc[4][4] = {};

  for (int kc = 0; kc < 8; ++kc) {
    const ushort* Ab = (kc < 4) ? aggb : xb;
    const int kco = (kc & 3) * 64;
    const int kbo = kc * 64;
    __syncthreads();
#pragma unroll
    for (int i = 0; i < 4; ++i) {
      const int c = w * 4 + i;
      if (c < 8) {
        int gr = row0 + c * 16 + srow;
        gr = (gr < N_NODES) ? gr : (N_NODES - 1);
        async_copy16((const char*)Ab + (size_t)gr * 256 + kco + sbyte,
                     (char*)As + c * 1024);
      } else {
        const int cb = c - 8;
        const int nr = col0 + cb * 16 + srow;
        async_copy16((const char*)WT + (size_t)nr * 512 + kbo + sbyte,
                     (char*)Bs + cb * 1024);
      }
    }
    __syncthreads();
    const int fr = l & 15;
    const int kg = (l >> 4) * 8;
    bf16x8 af[4], bfr[4];
#pragma unroll
    for (int i = 0; i < 4; ++i)
      af[i] = *(const bf16x8*)&As[(wm + i * 16 + fr) * 32 + kg];
#pragma unroll
    for (int j = 0; j < 4; ++j)
      bfr[j] = *(const bf16x8*)&Bs[(wn + j * 16 + fr) * 32 + kg];
#pragma unroll
    for (int i = 0; i < 4; ++i)
#pragma unroll
      for (int j = 0; j < 4; ++j)
        acc[i][j] = __builtin_amdgcn_mfma_f32_16x16x32_bf16(af[i], bfr[j],
                                                            acc[i][j], 0, 0, 0);
  }

  const int cr = (l >> 4) * 4;
  const int cc = l & 15;
#pragma unroll
  for (int i = 0; i < 4; ++i) {
    const int growb = row0 + wm + i * 16 + cr;
#pragma unroll
    for (int j = 0; j < 4; ++j) {
      const int gcol = col0 + wn + j * 16 + cc;
      const float bv = bias[gcol];
#pragma unroll
      for (int r = 0; r < 4; ++r) {
        const int grow = growb + r;
        if (grow < N_NODES) {
          const float v = fmaxf(acc[i][j][r] + bv, 0.f);
          h[(size_t)grow * 256 + gcol] = f2bf(v);
        }
      }
    }
  }
}

// ---------------------------------------------------------------------------
// MFMA GEMM, layer 2 fused: y==0 -> p = h@Wl2 (bf16); y==1 -> zp = h@Wr2+bl2.
// ---------------------------------------------------------------------------
__global__ __launch_bounds__(256) void gemm_l2(const ushort* __restrict__ h,
                                               const ushort* __restrict__ WT,
                                               const float* __restrict__ bias,
                                               ushort* __restrict__ p,
                                               float* __restrict__ zp) {
  __shared__ ushort As[4096];
  __shared__ ushort Bs[4096];
  const int tid = threadIdx.x;
  const int w = tid >> 6;
  const int l = tid & 63;
  const int row0 = blockIdx.x * 128;
  const int col0 = blockIdx.y * 128;
  const int wm = (w >> 1) * 64;
  const int wn = (w & 1) * 64;
  const int srow = l >> 2;
  const int sbyte = (l & 3) * 16;
  f32x4 acc[4][4] = {};

  for (int kc = 0; kc < 8; ++kc) {
    const int kbo = kc * 64;
    __syncthreads();
#pragma unroll
    for (int i = 0; i < 4; ++i) {
      const int c = w * 4 + i;
      if (c < 8) {
        int gr = row0 + c * 16 + srow;
        gr = (gr < N_NODES) ? gr : (N_NODES - 1);
        async_copy16((const char*)h + (size_t)gr * 512 + kbo + sbyte,
                     (char*)As + c * 1024);
      } else {
        const int cb = c - 8;
        const int nr = col0 + cb * 16 + srow;
        async_copy16((const char*)WT + (size_t)nr * 512 + kbo + sbyte,
                     (char*)Bs + cb * 1024);
      }
    }
    __syncthreads();
    const int fr = l & 15;
    const int kg = (l >> 4) * 8;
    bf16x8 af[4], bfr[4];
#pragma unroll
    for (int i = 0; i < 4; ++i)
      af[i] = *(const bf16x8*)&As[(wm + i * 16 + fr) * 32 + kg];
#pragma unroll
    for (int j = 0; j < 4; ++j)
      bfr[j] = *(const bf16x8*)&Bs[(wn + j * 16 + fr) * 32 + kg];
#pragma unroll
    for (int i = 0; i < 4; ++i)
#pragma unroll
      for (int j = 0; j < 4; ++j)
        acc[i][j] = __builtin_amdgcn_mfma_f32_16x16x32_bf16(af[i], bfr[j],
                                                            acc[i][j], 0, 0, 0);
  }

  const int cr = (l >> 4) * 4;
  const int cc = l & 15;
  const bool is_p = (blockIdx.y == 0);
#pragma unroll
  for (int i = 0; i < 4; ++i) {
    const int growb = row0 + wm + i * 16 + cr;
#pragma unroll
    for (int j = 0; j < 4; ++j) {
      const int gcl = wn + j * 16 + cc;
      const float bv = is_p ? 0.f : bias[gcl];
#pragma unroll
      for (int r = 0; r < 4; ++r) {
        const int grow = growb + r;
        if (grow < N_NODES) {
          const float v = acc[i][j][r] + bv;
          if (is_p)
            p[(size_t)grow * 128 + gcl] = f2bf(v);
          else
            zp[(size_t)grow * 128 + gcl] = v;
        }
      }
    }
  }
}

// ---------------------------------------------------------------------------
// Decode
// ---------------------------------------------------------------------------
__global__ __launch_bounds__(256) void dot_kernel(const int* __restrict__ ls,
                                                  const int* __restrict__ ld,
                                                  const float* __restrict__ z,
                                                  float* __restrict__ out) {
  long long tid = (long long)blockIdx.x * 256 + threadIdx.x;
  int e = (int)(tid >> 5);
  int lane = (int)(tid & 31);
  if (e >= N_LABEL) return;
  int a = ls[e], b = ld[e];
  const float4 va = *(const float4*)&z[(size_t)a * 128 + lane * 4];
  const float4 vb = *(const float4*)&z[(size_t)b * 128 + lane * 4];
  float p = va.x * vb.x + va.y * vb.y + va.z * vb.z + va.w * vb.w;
  p += __shfl_xor(p, 16, 32);
  p += __shfl_xor(p, 8, 32);
  p += __shfl_xor(p, 4, 32);
  p += __shfl_xor(p, 2, 32);
  p += __shfl_xor(p, 1, 32);
  if (lane == 0) out[e] = p;
}

extern "C" void kernel_launch(void* const* d_in, const int* in_sizes, int n_in,
                              void* d_out, int out_size, void* d_ws, size_t ws_size,
                              hipStream_t stream) {
  const float* x = (const float*)d_in[0];
  const int* ei = (const int*)d_in[1];
  const int* eli = (const int*)d_in[2];
  const float* Wl1 = (const float*)d_in[3];
  const float* bl1 = (const float*)d_in[4];
  const float* Wr1 = (const float*)d_in[5];
  const float* Wl2 = (const float*)d_in[6];
  const float* bl2 = (const float*)d_in[7];
  const float* Wr2 = (const float*)d_in[8];
  float* out = (float*)d_out;

  const int* e_src = ei;
  const int* e_dst = ei + N_EDGES;
  const int* l_src = eli;
  const int* l_dst = eli + N_LABEL;

  char* ws = (char*)d_ws;
  ushort* xb = (ushort*)(ws + 0);           //  25.6 MB
  ushort* aggb = (ushort*)(ws + 25600000);  //  25.6 MB
  ushort* h = (ushort*)(ws + 51200000);     //  51.2 MB
  ushort* p = (ushort*)(ws + 102400000);    //  25.6 MB
  float* z = (float*)(ws + 128000000);      //  51.2 MB
  ushort* WT1 = (ushort*)(ws + 179200000);  // 128 KB
  ushort* WT2 = (ushort*)(ws + 179331072);  // 128 KB
  uint* tmp = (uint*)(ws + 179462144);      // 6.4 MB packed edges -> csr_src
  int* cnt = (int*)(ws + 185862144);        // (FLEN+1) ints
  int* bsum = (int*)(ws + 186270000);       // 128 ints
  int* bpre = bsum + 128;                   // 128 ints
  int* row_start = (int*)(ws + 186280000);  // (N_NODES+1) ints

  const int SBLK = (FLEN + 1023) / 1024;  // 98

  // --- multisplit by dst>>6 + in-LDS per-bucket counting sort ---
  bucket_count<<<NBF, 256, 0, stream>>>(e_dst, cnt);
  scan_sums<FLEN><<<SBLK, 256, 0, stream>>>(cnt, bsum);
  scan_tops<<<1, 128, 0, stream>>>(bsum, bpre, &cnt[FLEN], SBLK);
  scan_apply<FLEN><<<SBLK, 256, 0, stream>>>(cnt, bpre);
  bucket_fill<<<NBF, 256, 0, stream>>>(e_src, e_dst, cnt, tmp);
  csr_build<<<NBUCK, 256, 0, stream>>>(cnt, tmp, row_start);

  // --- casts / weight prep ---
  cast_bf16<<<(N_NODES * C_IN) / (256 * 8), 256, 0, stream>>>(x, xb);
  prep_wt<<<256, 256, 0, stream>>>(Wl1, Wr1, Wl2, Wr2, WT1, WT2);

  // --- layer 1 ---
  gather_mean_b<0><<<(N_NODES + 3) / 4, 256, 0, stream>>>(row_start, tmp, xb,
                                                          aggb, nullptr);
  gemm_l1<<<dim3((N_NODES + 127) / 128, 2), 256, 0, stream>>>(aggb, xb, WT1, bl1, h);

  // --- layer 2 ---
  gemm_l2<<<dim3((N_NODES + 127) / 128, 2), 256, 0, stream>>>(h, WT2, bl2, p, z);
  gather_mean_b<1><<<(N_NODES + 3) / 4, 256, 0, stream>>>(row_start, tmp, p,
                                                          nullptr, z);

  // --- decode ---
  dot_kernel<<<(int)(((long long)N_LABEL * 32) / 256), 256, 0, stream>>>(
      l_src, l_dst, z, out);
}

// Round 9
// 334.153 us; speedup vs baseline: 7.7200x; 1.1054x over previous
//
#include <hip/hip_runtime.h>

#define N_NODES 100000
#define N_EDGES 1600000
#define N_LABEL 200000
#define C_IN 128
#define C_HID 256
#define C_OUT 128

#define BCHUNK 64                                 // nodes per bucket
#define NBUCK ((N_NODES + BCHUNK - 1) / BCHUNK)   // 1563
#define NBF 64                                    // multisplit blocks
#define EPB (N_EDGES / NBF)                       // 25000 edges per block
#define FLEN (NBUCK * NBF)                        // 100032 (bucket-major counts)
#define ESTORE 2048                               // max edges per bucket

typedef __attribute__((ext_vector_type(8))) short bf16x8;
typedef __attribute__((ext_vector_type(4))) float f32x4;

__device__ __forceinline__ ushort f2bf(float f) {  // RTNE
  uint u = __float_as_uint(f);
  return (ushort)((u + 0x7fffu + ((u >> 16) & 1u)) >> 16);
}

__device__ __forceinline__ float bfl(uint u) { return __uint_as_float(u << 16); }
__device__ __forceinline__ float bfh(uint u) {
  return __uint_as_float(u & 0xffff0000u);
}

__device__ __forceinline__ void async_copy16(const void* g, void* lds) {
  __builtin_amdgcn_global_load_lds((const __attribute__((address_space(1))) void*)g,
                                   (__attribute__((address_space(3))) void*)lds,
                                   16, 0, 0);
}

// ---------------------------------------------------------------------------
// Multisplit P1: per-(block,bucket) histogram in LDS (chains ~16).
// ---------------------------------------------------------------------------
__global__ __launch_bounds__(256) void bucket_count(const int* __restrict__ dst,
                                                    int* __restrict__ cnt) {
  __shared__ int lcnt[NBUCK];
  const int t = threadIdx.x;
  const int base = blockIdx.x * EPB;
  for (int b = t; b < NBUCK; b += 256) lcnt[b] = 0;
  __syncthreads();
  for (int i = t; i < EPB; i += 256) {
    atomicAdd(&lcnt[dst[base + i] >> 6], 1);
  }
  __syncthreads();
  for (int b = t; b < NBUCK; b += 256) cnt[b * NBF + blockIdx.x] = lcnt[b];
}

// ---------------------------------------------------------------------------
// 3-phase exclusive scan over cnt (length FLEN), in place.
// ---------------------------------------------------------------------------
template <int LEN>
__global__ __launch_bounds__(256) void scan_sums(const int* __restrict__ a,
                                                 int* __restrict__ bsum) {
  __shared__ int red[256];
  const int t = threadIdx.x;
  const int idx = blockIdx.x * 1024 + t * 4;
  int s = 0;
  if (idx + 3 < LEN) {
    const int4 v = *(const int4*)&a[idx];
    s = v.x + v.y + v.z + v.w;
  } else {
    for (int j = 0; j < 4 && idx + j < LEN; ++j) s += a[idx + j];
  }
  red[t] = s;
  __syncthreads();
  for (int off = 128; off > 0; off >>= 1) {
    if (t < off) red[t] += red[t + off];
    __syncthreads();
  }
  if (t == 0) bsum[blockIdx.x] = red[0];
}

__global__ __launch_bounds__(128) void scan_tops(const int* __restrict__ bsum,
                                                 int* __restrict__ bpre,
                                                 int* __restrict__ total, int nb) {
  __shared__ int sh[128];
  const int t = threadIdx.x;
  sh[t] = (t < nb) ? bsum[t] : 0;
  __syncthreads();
  for (int off = 1; off < 128; off <<= 1) {
    int v = 0;
    if (t >= off) v = sh[t - off];
    __syncthreads();
    if (t >= off) sh[t] += v;
    __syncthreads();
  }
  if (t < nb) bpre[t] = (t == 0) ? 0 : sh[t - 1];
  if (t == nb - 1) *total = sh[t];
}

template <int LEN>
__global__ __launch_bounds__(256) void scan_apply(int* __restrict__ a,
                                                  const int* __restrict__ bpre) {
  __shared__ int sh[256];
  const int t = threadIdx.x;
  const int idx = blockIdx.x * 1024 + t * 4;
  int4 v = make_int4(0, 0, 0, 0);
  const bool full = (idx + 3 < LEN);
  if (full) {
    v = *(const int4*)&a[idx];
  } else {
    if (idx + 0 < LEN) v.x = a[idx + 0];
    if (idx + 1 < LEN) v.y = a[idx + 1];
    if (idx + 2 < LEN) v.z = a[idx + 2];
    if (idx + 3 < LEN) v.w = a[idx + 3];
  }
  sh[t] = v.x + v.y + v.z + v.w;
  __syncthreads();
  for (int off = 1; off < 256; off <<= 1) {
    int u = 0;
    if (t >= off) u = sh[t - off];
    __syncthreads();
    if (t >= off) sh[t] += u;
    __syncthreads();
  }
  const int base = bpre[blockIdx.x] + ((t == 0) ? 0 : sh[t - 1]);
  int4 e;
  e.x = base;
  e.y = base + v.x;
  e.z = base + v.x + v.y;
  e.w = base + v.x + v.y + v.z;
  if (full) {
    *(int4*)&a[idx] = e;
  } else {
    if (idx + 0 < LEN) a[idx + 0] = e.x;
    if (idx + 1 < LEN) a[idx + 1] = e.y;
    if (idx + 2 < LEN) a[idx + 2] = e.z;
    if (idx + 3 < LEN) a[idx + 3] = e.w;
  }
}

// ---------------------------------------------------------------------------
// Multisplit P3: deterministic bucket scatter with LDS cursors.
// ---------------------------------------------------------------------------
__global__ __launch_bounds__(256) void bucket_fill(const int* __restrict__ src,
                                                   const int* __restrict__ dst,
                                                   const int* __restrict__ cnt,
                                                   uint* __restrict__ tmp) {
  __shared__ int lcur[NBUCK];
  const int t = threadIdx.x;
  const int base = blockIdx.x * EPB;
  for (int b = t; b < NBUCK; b += 256) lcur[b] = cnt[b * NBF + blockIdx.x];
  __syncthreads();
  for (int i = t; i < EPB; i += 256) {
    const int d = dst[base + i];
    const int s = src[base + i];
    const int pos = atomicAdd(&lcur[d >> 6], 1);
    tmp[pos] = ((uint)s << 6) | (uint)(d & 63);
  }
}

// ---------------------------------------------------------------------------
// Per-bucket CSR finalize, in LDS; tmp becomes csr_src in place.
// ---------------------------------------------------------------------------
__global__ __launch_bounds__(256) void csr_build(const int* __restrict__ cnt,
                                                 uint* __restrict__ tmp,
                                                 int* __restrict__ row_start) {
  __shared__ uint est[ESTORE];
  __shared__ uint eso[ESTORE];
  __shared__ int lcnt[BCHUNK];
  __shared__ int lcur[BCHUNK];
  const int b = blockIdx.x;
  const int t = threadIdx.x;
  const int s = cnt[b * NBF];
  const int e = cnt[(b + 1) * NBF];
  const int n = e - s;
  for (int j = t; j < n; j += 256) est[j] = tmp[s + j];
  if (t < BCHUNK) lcnt[t] = 0;
  __syncthreads();
  for (int j = t; j < n; j += 256) atomicAdd(&lcnt[est[j] & 63], 1);
  __syncthreads();
  for (int off = 1; off < BCHUNK; off <<= 1) {
    int v = 0;
    if (t >= off && t < BCHUNK) v = lcnt[t - off];
    __syncthreads();
    if (t >= off && t < BCHUNK) lcnt[t] += v;
    __syncthreads();
  }
  if (t < BCHUNK) {
    const int ex = (t == 0) ? 0 : lcnt[t - 1];
    lcur[t] = ex;
    const int node = b * BCHUNK + t;
    if (node < N_NODES) row_start[node] = s + ex;
  }
  if (b == NBUCK - 1 && t == 0) row_start[N_NODES] = e;
  __syncthreads();
  for (int j = t; j < n; j += 256) {
    const uint v = est[j];
    const int pos = atomicAdd(&lcur[v & 63], 1);
    eso[pos] = v >> 6;
  }
  __syncthreads();
  for (int j = t; j < n; j += 256) tmp[s + j] = eso[j];
}

// ---------------------------------------------------------------------------
// fp32 -> bf16 cast (8 elems / thread)
// ---------------------------------------------------------------------------
__global__ __launch_bounds__(256) void cast_bf16(const float* __restrict__ in,
                                                 ushort* __restrict__ out) {
  const size_t i = ((size_t)blockIdx.x * 256 + threadIdx.x) * 8;
  const float4 a = *(const float4*)&in[i];
  const float4 b = *(const float4*)&in[i + 4];
  uint4 o;
  o.x = (uint)f2bf(a.x) | ((uint)f2bf(a.y) << 16);
  o.y = (uint)f2bf(a.z) | ((uint)f2bf(a.w) << 16);
  o.z = (uint)f2bf(b.x) | ((uint)f2bf(b.y) << 16);
  o.w = (uint)f2bf(b.z) | ((uint)f2bf(b.w) << 16);
  *(uint4*)&out[i] = o;
}

// ---------------------------------------------------------------------------
// Weight prep (N-major bf16)
// ---------------------------------------------------------------------------
__global__ __launch_bounds__(256) void prep_wt(const float* __restrict__ Wl1,
                                               const float* __restrict__ Wr1,
                                               const float* __restrict__ Wl2,
                                               const float* __restrict__ Wr2,
                                               ushort* __restrict__ WT1,
                                               ushort* __restrict__ WT2) {
  const int n = blockIdx.x;
  const int k = threadIdx.x;
  const float v1 = (k < 128) ? Wl1[k * 256 + n] : Wr1[(k - 128) * 256 + n];
  WT1[n * 256 + k] = f2bf(v1);
  const float v2 = (n < 128) ? Wl2[k * 128 + n] : Wr2[k * 128 + (n - 128)];
  WT2[n * 256 + k] = f2bf(v2);
}

// ---------------------------------------------------------------------------
// Mean aggregation: one wave per node; 4 edge-slots x 16 lanes x bf16x8
// (16B/lane); unroll x4 -> 16 rows in flight per wave.
// MODE 0: write bf16 mean.  MODE 1: z[node] += mean (fp32, in place).
// ---------------------------------------------------------------------------
template <int MODE>
__global__ __launch_bounds__(256) void gather_mean_b(const int* __restrict__ row_start,
                                                     const uint* __restrict__ csr_src,
                                                     const ushort* __restrict__ feat,
                                                     ushort* __restrict__ bout,
                                                     float* __restrict__ z) {
  const int wid = blockIdx.x * 4 + (threadIdx.x >> 6);
  const int lane = threadIdx.x & 63;
  if (wid >= N_NODES) return;
  const int s = row_start[wid];
  const int e = row_start[wid + 1];
  const int slot = lane >> 4;
  const int c0 = (lane & 15) * 8;
  float acc[8] = {};
  int j = s + slot;
#define ACC8(r)                                   \
  acc[0] += bfl(r.x); acc[1] += bfh(r.x);         \
  acc[2] += bfl(r.y); acc[3] += bfh(r.y);         \
  acc[4] += bfl(r.z); acc[5] += bfh(r.z);         \
  acc[6] += bfl(r.w); acc[7] += bfh(r.w);
  for (; j + 12 < e; j += 16) {
    const uint s0 = csr_src[j];
    const uint s1 = csr_src[j + 4];
    const uint s2 = csr_src[j + 8];
    const uint s3 = csr_src[j + 12];
    const uint4 r0 = *(const uint4*)&feat[(size_t)s0 * 128 + c0];
    const uint4 r1 = *(const uint4*)&feat[(size_t)s1 * 128 + c0];
    const uint4 r2 = *(const uint4*)&feat[(size_t)s2 * 128 + c0];
    const uint4 r3 = *(const uint4*)&feat[(size_t)s3 * 128 + c0];
    ACC8(r0) ACC8(r1) ACC8(r2) ACC8(r3)
  }
  for (; j < e; j += 4) {
    const uint s0 = csr_src[j];
    const uint4 r0 = *(const uint4*)&feat[(size_t)s0 * 128 + c0];
    ACC8(r0)
  }
#undef ACC8
#pragma unroll
  for (int k = 0; k < 8; ++k) {
    acc[k] += __shfl_xor(acc[k], 16, 64);
    acc[k] += __shfl_xor(acc[k], 32, 64);
  }
  if (slot == 0) {
    const float rd = 1.0f / fmaxf((float)(e - s), 1.0f);
    if (MODE == 0) {
      uint4 o;
      o.x = (uint)f2bf(acc[0] * rd) | ((uint)f2bf(acc[1] * rd) << 16);
      o.y = (uint)f2bf(acc[2] * rd) | ((uint)f2bf(acc[3] * rd) << 16);
      o.z = (uint)f2bf(acc[4] * rd) | ((uint)f2bf(acc[5] * rd) << 16);
      o.w = (uint)f2bf(acc[6] * rd) | ((uint)f2bf(acc[7] * rd) << 16);
      *(uint4*)&bout[(size_t)wid * 128 + c0] = o;
    } else {
      float4 z0 = *(const float4*)&z[(size_t)wid * 128 + c0];
      float4 z1 = *(const float4*)&z[(size_t)wid * 128 + c0 + 4];
      z0.x += acc[0] * rd; z0.y += acc[1] * rd;
      z0.z += acc[2] * rd; z0.w += acc[3] * rd;
      z1.x += acc[4] * rd; z1.y += acc[5] * rd;
      z1.z += acc[6] * rd; z1.w += acc[7] * rd;
      *(float4*)&z[(size_t)wid * 128 + c0] = z0;
      *(float4*)&z[(size_t)wid * 128 + c0 + 4] = z1;
    }
  }
}

// ---------------------------------------------------------------------------
// Fused MLP chain: per 64-row block,
//   phase 1: h = relu([aggb|xb] @ WT1 + bl1)    -> swizzled LDS (never HBM)
//   phase 2: [p | zp] = h @ WT2 (+bl2 on zp)    -> global
// 256 threads = 4 waves; each wave owns a 64-col slice in both phases.
// h_tile LDS is XOR-swizzled (byte ^= (row&7)<<4) so phase-2 A-fragment
// ds_read_b128 at row-stride 512B lands 2-way (free) instead of 16-way.
// ---------------------------------------------------------------------------
__global__ __launch_bounds__(256) void gemm_fused(const ushort* __restrict__ aggb,
                                                  const ushort* __restrict__ xb,
                                                  const ushort* __restrict__ WT1,
                                                  const ushort* __restrict__ WT2,
                                                  const float* __restrict__ bl1,
                                                  const float* __restrict__ bl2,
                                                  ushort* __restrict__ p,
                                                  float* __restrict__ zp) {
  __shared__ ushort As[2048];       // 64 rows x 32 k   (4 KB)
  __shared__ ushort Bs[8192];       // 256 n  x 32 k   (16 KB)
  __shared__ ushort Ht[64 * 256];   // h tile, swizzled (32 KB)
  const int tid = threadIdx.x;
  const int w = tid >> 6;           // 0..3
  const int l = tid & 63;
  const int row0 = blockIdx.x * 64;
  const int wn = w * 64;            // wave's col slice
  const int srow = l >> 2;          // 0..15
  const int sbyte = (l & 3) * 16;
  const int fr = l & 15;
  const int kg8 = (l >> 4) * 8;     // elem offset in 32-k step
  const int cr = (l >> 4) * 4;
  const int cc = l & 15;

  // ---- phase 1: h_tile = relu([aggb|xb] @ WT1 + bl1) ----
  {
    f32x4 acc[4][4] = {};
    for (int kc = 0; kc < 8; ++kc) {
      const ushort* Ab = (kc < 4) ? aggb : xb;
      const int kco = (kc & 3) * 64;  // byte offset in 256B A row
      const int kbo = kc * 64;        // byte offset in 512B WT1 row
      __syncthreads();
      {  // A: 64x32 (4KB), chunk per wave
        int gr = row0 + w * 16 + srow;
        gr = (gr < N_NODES) ? gr : (N_NODES - 1);
        async_copy16((const char*)Ab + (size_t)gr * 256 + kco + sbyte,
                     (char*)As + w * 1024);
      }
#pragma unroll
      for (int i = 0; i < 4; ++i) {  // B: 256x32 (16KB), 4 chunks per wave
        const int c = w * 4 + i;
        const int nr = c * 16 + srow;
        async_copy16((const char*)WT1 + (size_t)nr * 512 + kbo + sbyte,
                     (char*)Bs + c * 1024);
      }
      __syncthreads();
      bf16x8 af[4], bfr[4];
#pragma unroll
      for (int i = 0; i < 4; ++i)
        af[i] = *(const bf16x8*)&As[(i * 16 + fr) * 32 + kg8];
#pragma unroll
      for (int j = 0; j < 4; ++j)
        bfr[j] = *(const bf16x8*)&Bs[(wn + j * 16 + fr) * 32 + kg8];
#pragma unroll
      for (int i = 0; i < 4; ++i)
#pragma unroll
        for (int j = 0; j < 4; ++j)
          acc[i][j] = __builtin_amdgcn_mfma_f32_16x16x32_bf16(af[i], bfr[j],
                                                              acc[i][j], 0, 0, 0);
    }
    // epilogue: bias + relu -> swizzled LDS h_tile
#pragma unroll
    for (int i = 0; i < 4; ++i) {
#pragma unroll
      for (int j = 0; j < 4; ++j) {
        const int col = wn + j * 16 + cc;
        const float bv = bl1[col];
#pragma unroll
        for (int r = 0; r < 4; ++r) {
          const int row = i * 16 + cr + r;
          const float v = fmaxf(acc[i][j][r] + bv, 0.f);
          const int ba = (row * 512 + col * 2) ^ ((row & 7) << 4);
          *(ushort*)((char*)Ht + ba) = f2bf(v);
        }
      }
    }
  }
  __syncthreads();

  // ---- phase 2: [p | zp] = h_tile @ WT2 ----
  f32x4 acc2[4][4] = {};
  for (int kc = 0; kc < 8; ++kc) {
    bf16x8 af[4], bfr[4];
#pragma unroll
    for (int i = 0; i < 4; ++i) {
      const int row = i * 16 + fr;
      const int ba = (row * 512 + kc * 64 + kg8 * 2) ^ ((row & 7) << 4);
      af[i] = *(const bf16x8*)((const char*)Ht + ba);
    }
#pragma unroll
    for (int j = 0; j < 4; ++j) {  // WT2 direct from L2 (128KB, shared by grid)
      const int n = wn + j * 16 + fr;
      bfr[j] = *(const bf16x8*)&WT2[(size_t)n * 256 + kc * 32 + kg8];
    }
#pragma unroll
    for (int i = 0; i < 4; ++i)
#pragma unroll
      for (int j = 0; j < 4; ++j)
        acc2[i][j] = __builtin_amdgcn_mfma_f32_16x16x32_bf16(af[i], bfr[j],
                                                             acc2[i][j], 0, 0, 0);
  }
#pragma unroll
  for (int i = 0; i < 4; ++i) {
#pragma unroll
    for (int j = 0; j < 4; ++j) {
      const int col = wn + j * 16 + cc;  // 0..255; <128 -> p, >=128 -> zp
      const int gcl = col & 127;
      const bool is_p = (col < 128);
      const float bv = is_p ? 0.f : bl2[gcl];
#pragma unroll
      for (int r = 0; r < 4; ++r) {
        const int grow = row0 + i * 16 + cr + r;
        if (grow < N_NODES) {
          const float v = acc2[i][j][r] + bv;
          if (is_p)
            p[(size_t)grow * 128 + gcl] = f2bf(v);
          else
            zp[(size_t)grow * 128 + gcl] = v;
        }
      }
    }
  }
}

// ---------------------------------------------------------------------------
// Decode
// ---------------------------------------------------------------------------
__global__ __launch_bounds__(256) void dot_kernel(const int* __restrict__ ls,
                                                  const int* __restrict__ ld,
                                                  const float* __restrict__ z,
                                                  float* __restrict__ out) {
  long long tid = (long long)blockIdx.x * 256 + threadIdx.x;
  int e = (int)(tid >> 5);
  int lane = (int)(tid & 31);
  if (e >= N_LABEL) return;
  int a = ls[e], b = ld[e];
  const float4 va = *(const float4*)&z[(size_t)a * 128 + lane * 4];
  const float4 vb = *(const float4*)&z[(size_t)b * 128 + lane * 4];
  float p = va.x * vb.x + va.y * vb.y + va.z * vb.z + va.w * vb.w;
  p += __shfl_xor(p, 16, 32);
  p += __shfl_xor(p, 8, 32);
  p += __shfl_xor(p, 4, 32);
  p += __shfl_xor(p, 2, 32);
  p += __shfl_xor(p, 1, 32);
  if (lane == 0) out[e] = p;
}

extern "C" void kernel_launch(void* const* d_in, const int* in_sizes, int n_in,
                              void* d_out, int out_size, void* d_ws, size_t ws_size,
                              hipStream_t stream) {
  const float* x = (const float*)d_in[0];
  const int* ei = (const int*)d_in[1];
  const int* eli = (const int*)d_in[2];
  const float* Wl1 = (const float*)d_in[3];
  const float* bl1 = (const float*)d_in[4];
  const float* Wr1 = (const float*)d_in[5];
  const float* Wl2 = (const float*)d_in[6];
  const float* bl2 = (const float*)d_in[7];
  const float* Wr2 = (const float*)d_in[8];
  float* out = (float*)d_out;

  const int* e_src = ei;
  const int* e_dst = ei + N_EDGES;
  const int* l_src = eli;
  const int* l_dst = eli + N_LABEL;

  char* ws = (char*)d_ws;
  ushort* xb = (ushort*)(ws + 0);           //  25.6 MB
  ushort* aggb = (ushort*)(ws + 25600000);  //  25.6 MB
  ushort* p = (ushort*)(ws + 102400000);    //  25.6 MB
  float* z = (float*)(ws + 128000000);      //  51.2 MB
  ushort* WT1 = (ushort*)(ws + 179200000);  // 128 KB
  ushort* WT2 = (ushort*)(ws + 179331072);  // 128 KB
  uint* tmp = (uint*)(ws + 179462144);      // 6.4 MB packed edges -> csr_src
  int* cnt = (int*)(ws + 185862144);        // (FLEN+1) ints
  int* bsum = (int*)(ws + 186270000);       // 128 ints
  int* bpre = bsum + 128;                   // 128 ints
  int* row_start = (int*)(ws + 186280000);  // (N_NODES+1) ints

  const int SBLK = (FLEN + 1023) / 1024;  // 98

  // --- multisplit by dst>>6 + in-LDS per-bucket counting sort ---
  bucket_count<<<NBF, 256, 0, stream>>>(e_dst, cnt);
  scan_sums<FLEN><<<SBLK, 256, 0, stream>>>(cnt, bsum);
  scan_tops<<<1, 128, 0, stream>>>(bsum, bpre, &cnt[FLEN], SBLK);
  scan_apply<FLEN><<<SBLK, 256, 0, stream>>>(cnt, bpre);
  bucket_fill<<<NBF, 256, 0, stream>>>(e_src, e_dst, cnt, tmp);
  csr_build<<<NBUCK, 256, 0, stream>>>(cnt, tmp, row_start);

  // --- casts / weight prep ---
  cast_bf16<<<(N_NODES * C_IN) / (256 * 8), 256, 0, stream>>>(x, xb);
  prep_wt<<<256, 256, 0, stream>>>(Wl1, Wr1, Wl2, Wr2, WT1, WT2);

  // --- layer 1 aggregation ---
  gather_mean_b<0><<<(N_NODES + 3) / 4, 256, 0, stream>>>(row_start, tmp, xb,
                                                          aggb, nullptr);
  // --- fused MLP chain: h (LDS-only) -> p, zp ---
  gemm_fused<<<(N_NODES + 63) / 64, 256, 0, stream>>>(aggb, xb, WT1, WT2, bl1,
                                                      bl2, p, z);
  // --- layer 2 aggregation: z += mean(p[neighbors]) ---
  gather_mean_b<1><<<(N_NODES + 3) / 4, 256, 0, stream>>>(row_start, tmp, p,
                                                          nullptr, z);

  // --- decode ---
  dot_kernel<<<(int)(((long long)N_LABEL * 32) / 256), 256, 0, stream>>>(
      l_src, l_dst, z, out);
}